// Round 11
// baseline (249.097 us; speedup 1.0000x reference)
//
#include <hip/hip_runtime.h>
#include <hip/hip_fp16.h>
#include <cmath>

// Radon backprojection, two-phase:
//   1) pack: zero-padded fp16 (v[j-1],v[j]) pair table [A][PES] (4 batches
//      per 16B entry) + trig table + zeroing of tile counters.
//   2) partial gather (ACHUNKS=8 chunk-blocks per pixel tile, fdot2 inner
//      loop, no in-loop barriers) with SPLIT-K LAST-BLOCK REDUCE: per-tile
//      device atomic counter; the 8th block to finish sums the 8 partials
//      and writes out. Removes the separate reduce launch + drain.
//
// R10 post-mortem: partial gather ~6-8us; the rest of "ours" (~26us over the
// ~50us harness floor) is launch gaps + latency-bound pack + reduce tail.

#define ACHUNKS 8

typedef __fp16 half2v __attribute__((ext_vector_type(2)));

__device__ __forceinline__ half2v as_h2(unsigned u) {
    union { unsigned u; half2v h; } x; x.u = u; return x.h;
}

__global__ __launch_bounds__(256) void radon_pack(
    const float* __restrict__ sino,
    const float* __restrict__ thetas,
    const float* __restrict__ positions,
    uint4* __restrict__ packed,        // [A][PES]; entry j: (v[j-1], v[j]) x4
    float2* __restrict__ trig,         // [A+1]; trig[A].x = q0
    int* __restrict__ cnt,             // [nnb] tile counters -> zero
    int A, int P, int PES, int bstride, int nnb)
{
    const int gidx = blockIdx.x * 256 + threadIdx.x;
    if (gidx < nnb) cnt[gidx] = 0;

    const int a = gidx / PES;
    const int j = gidx - a * PES;
    if (a >= A) return;

    const float p0     = positions[0];
    const float inv_dp = 1.0f / (positions[1] - p0);
    if (j == 0) {
        float th = thetas[a];
        trig[a] = make_float2(cosf(th) * inv_dp, sinf(th) * inv_dp);
        if (a == 0) trig[A] = make_float2(-p0 * inv_dp, 0.0f);
    }

    uint4 e = make_uint4(0, 0, 0, 0);
    if (j >= 1 && j <= P - 1) {
        const float* s = sino + (size_t)a * P + (j - 1);
        unsigned* ep = (unsigned*)&e;
#pragma unroll
        for (int b = 0; b < 4; ++b) {
            float2 v = *(const float2*)(s + (size_t)b * bstride); // dwordx2
            half2v h = __builtin_amdgcn_cvt_pkrtz(v.x, v.y);      // lo=v0 hi=v1
            union { half2v h; unsigned u; } cvt; cvt.h = h;
            ep[b] = cvt.u;
        }
    }
    packed[(size_t)a * PES + j] = e;
}

__global__ __launch_bounds__(256) void radon_partial_sk(
    const uint4* __restrict__ packed,  // [A][PES]
    const float2* __restrict__ trig,   // [A+1]
    float* __restrict__ part,          // [ACHUNKS][4][nn]
    int* __restrict__ cnt,             // [nnb]
    float* __restrict__ out,           // [4][nn]
    int A, int P, int PES, int N, int chunk)
{
    __shared__ int s_old;
    const int tid = threadIdx.x;
    const int nn  = N * N;
    const int pix = blockIdx.x * 256 + tid;
    const int c   = blockIdx.y;
    const int a0  = c * chunk;
    const int a1  = min(A, a0 + chunk);

    const int x = pix % N;
    const int y = pix / N;
    const float half = (float)(N - 1) * 0.5f;
    const float cx = (float)x - half;
    const float cy = half - (float)y;
    const float q0 = trig[A].x;        // uniform -> s_load

    float acc0 = 0.f, acc1 = 0.f, acc2 = 0.f, acc3 = 0.f;

#pragma unroll 4
    for (int a = a0; a < a1; ++a) {
        float2 t  = trig[a];           // uniform -> s_load_dwordx2
        float f   = fmaf(cx, t.x, fmaf(cy, t.y, q0));
        float i0f = floorf(f);
        float w   = f - i0f;
        int   i0  = (int)i0f;
        int   j   = min(max(i0, -1), P - 1) + 1;   // borders -> zero entries

        half2v w2 = __builtin_amdgcn_cvt_pkrtz(1.0f - w, w);   // (om, wm)
        uint4 e = packed[(size_t)a * PES + j];      // global_load_dwordx4
        acc0 = __builtin_amdgcn_fdot2(as_h2(e.x), w2, acc0, false);
        acc1 = __builtin_amdgcn_fdot2(as_h2(e.y), w2, acc1, false);
        acc2 = __builtin_amdgcn_fdot2(as_h2(e.z), w2, acc2, false);
        acc3 = __builtin_amdgcn_fdot2(as_h2(e.w), w2, acc3, false);
    }

    // Store this chunk's partials.
    float* pp = part + (size_t)c * 4 * nn + pix;
    pp[0]              = acc0;
    pp[(size_t)nn]     = acc1;
    pp[(size_t)2 * nn] = acc2;
    pp[(size_t)3 * nn] = acc3;

    // Split-k completion: last block for this tile does the reduction.
    __threadfence();                   // release partials (device scope)
    __syncthreads();
    if (tid == 0)
        s_old = atomicAdd(&cnt[blockIdx.x], 1);
    __syncthreads();
    if (s_old == (int)gridDim.y - 1) {
        __threadfence();               // acquire other blocks' partials
        float r0 = 0.f, r1 = 0.f, r2 = 0.f, r3 = 0.f;
#pragma unroll
        for (int cc = 0; cc < ACHUNKS; ++cc) {
            const float* qp = part + (size_t)cc * 4 * nn + pix;
            r0 += qp[0];
            r1 += qp[(size_t)nn];
            r2 += qp[(size_t)2 * nn];
            r3 += qp[(size_t)3 * nn];
        }
        float* op = out + pix;
        op[0]              = r0;
        op[(size_t)nn]     = r1;
        op[(size_t)2 * nn] = r2;
        op[(size_t)3 * nn] = r3;
    }
}

// Generic fallback: direct per-batch kernel (any shape).
__global__ __launch_bounds__(256) void radon_direct_kernel(
    const float* __restrict__ sino,
    const float* __restrict__ thetas,
    const float* __restrict__ positions,
    float* __restrict__ out,
    int A, int P, int N, int BC)
{
    const int nn  = N * N;
    const int pix = blockIdx.x * blockDim.x + threadIdx.x;
    if (pix >= nn) return;
    const float p0     = positions[0];
    const float inv_dp = 1.0f / (positions[1] - p0);
    const int x = pix % N;
    const int y = pix / N;
    const float half = (float)(N - 1) * 0.5f;
    const float cx = (float)x - half;
    const float cy = half - (float)y;
    for (int b = 0; b < BC; ++b) {
        float acc = 0.0f;
        for (int a = 0; a < A; ++a) {
            float th = thetas[a];
            float f  = (cx * cosf(th) + cy * sinf(th) - p0) * inv_dp;
            float i0f = floorf(f);
            int i0 = (int)i0f;
            float w = f - i0f;
            float m = (i0 >= 0 && i0 <= P - 2) ? 1.0f : 0.0f;
            int ic = min(max(i0, 0), P - 2);
            const float* row = sino + ((size_t)b * A + a) * P + ic;
            acc = fmaf(m, fmaf(w, row[1] - row[0], row[0]), acc);
        }
        out[(size_t)b * nn + pix] = acc;
    }
}

extern "C" void kernel_launch(void* const* d_in, const int* in_sizes, int n_in,
                              void* d_out, int out_size, void* d_ws, size_t ws_size,
                              hipStream_t stream) {
    const float* sino      = (const float*)d_in[0];
    const float* thetas    = (const float*)d_in[1];
    const float* positions = (const float*)d_in[2];
    float* out             = (float*)d_out;

    const int A  = in_sizes[1];               // 180
    const int P  = in_sizes[2];               // 384
    const int BC = in_sizes[0] / (A * P);     // B*C = 4
    const int N  = (int)lroundf(sqrtf((float)(out_size / BC)));
    const int nn = N * N;
    const int bstride = A * P;

    const int PES   = (P + 2 + 63) & ~63;     // padded entries per angle
    const int chunk = (A + ACHUNKS - 1) / ACHUNKS;
    const int nnb   = nn / 256;               // pixel tiles

    const size_t cnt_bytes    = ((size_t)nnb * sizeof(int) + 1023) & ~(size_t)1023;
    const size_t part_bytes   = (size_t)ACHUNKS * 4 * nn * sizeof(float);
    const size_t packed_bytes = (size_t)A * PES * sizeof(uint4);
    const size_t trig_bytes   = (size_t)(A + 1) * sizeof(float2);
    const size_t need = cnt_bytes + part_bytes + packed_bytes + trig_bytes;

    const bool fast = (BC == 4) && (A <= 1024) && (P >= 2)
                   && ((nn & 255) == 0) && (ws_size >= need)
                   && ((size_t)A * PES >= (size_t)nnb);

    if (fast) {
        int*    cnt    = (int*)d_ws;
        float*  part   = (float*)((char*)d_ws + cnt_bytes);
        uint4*  packed = (uint4*)((char*)d_ws + cnt_bytes + part_bytes);
        float2* trig   = (float2*)((char*)d_ws + cnt_bytes + part_bytes + packed_bytes);

        dim3 block(256);
        dim3 gpack(((unsigned)(A * PES) + 255) / 256);
        radon_pack<<<gpack, block, 0, stream>>>(
            sino, thetas, positions, packed, trig, cnt, A, P, PES, bstride, nnb);

        dim3 gpart(nn / 256, ACHUNKS);
        radon_partial_sk<<<gpart, block, 0, stream>>>(
            packed, trig, part, cnt, out, A, P, PES, N, chunk);
    } else {
        dim3 block(256);
        dim3 grid((nn + 255) / 256);
        radon_direct_kernel<<<grid, block, 0, stream>>>(
            sino, thetas, positions, out, A, P, N, BC);
    }
}

// Round 12
// 72.656 us; speedup vs baseline: 3.4285x; 3.4285x over previous
//
#include <hip/hip_runtime.h>
#include <hip/hip_fp16.h>
#include <cmath>

// Radon backprojection, TWO dispatches:
//   1) pack: zero-padded fp16 (v[j-1],v[j]) pair table [A][PES] (4 batches
//      per 16B entry) + trig table + ZEROES out (float4/thread).
//   2) chunked gather (ACHUNKS=8 -> 32 waves/CU, fdot2 loop, no barriers),
//      committing with 4 plain atomicAdds/thread (device-scope, NO fences).
//
// R11 post-mortem: split-k last-block reduce with per-block __threadfence()
// = L2 flush storm across 8 XCDs -> 193us kernel. NEVER per-block device
// fences on MI355X. R2->R3 showed the plain-atomic epilogue is ~cost-neutral
// vs partial stores + reduce; using it here removes the 3rd launch (~5-10us
// of launch overhead) and the 8MB partial round-trip.

#define ACHUNKS 8

typedef __fp16 half2v __attribute__((ext_vector_type(2)));

__device__ __forceinline__ half2v as_h2(unsigned u) {
    union { unsigned u; half2v h; } x; x.u = u; return x.h;
}

__global__ __launch_bounds__(256) void radon_pack_zero(
    const float* __restrict__ sino,
    const float* __restrict__ thetas,
    const float* __restrict__ positions,
    uint4* __restrict__ packed,        // [A][PES]; entry j: (v[j-1], v[j]) x4
    float2* __restrict__ trig,         // [A+1]; trig[A].x = q0
    float4* __restrict__ out4,         // [nn] float4s (= [4][nn] floats) -> zero
    int A, int P, int PES, int bstride, int nout4)
{
    const int gidx = blockIdx.x * 256 + threadIdx.x;
    if (gidx < nout4) out4[gidx] = make_float4(0.f, 0.f, 0.f, 0.f);

    const int a = gidx / PES;
    const int j = gidx - a * PES;
    if (a >= A) return;

    const float p0     = positions[0];
    const float inv_dp = 1.0f / (positions[1] - p0);
    if (j == 0) {
        float th = thetas[a];
        trig[a] = make_float2(cosf(th) * inv_dp, sinf(th) * inv_dp);
        if (a == 0) trig[A] = make_float2(-p0 * inv_dp, 0.0f);
    }

    uint4 e = make_uint4(0, 0, 0, 0);
    if (j >= 1 && j <= P - 1) {
        const float* s = sino + (size_t)a * P + (j - 1);
        unsigned* ep = (unsigned*)&e;
#pragma unroll
        for (int b = 0; b < 4; ++b) {
            float2 v = *(const float2*)(s + (size_t)b * bstride); // dwordx2
            half2v h = __builtin_amdgcn_cvt_pkrtz(v.x, v.y);      // lo=v0 hi=v1
            union { half2v h; unsigned u; } cvt; cvt.h = h;
            ep[b] = cvt.u;
        }
    }
    packed[(size_t)a * PES + j] = e;
}

__global__ __launch_bounds__(256) void radon_gather_at(
    const uint4* __restrict__ packed,  // [A][PES]
    const float2* __restrict__ trig,   // [A+1]
    float* __restrict__ out,           // [4][nn], pre-zeroed
    int A, int P, int PES, int N, int chunk)
{
    const int tid = threadIdx.x;
    const int nn  = N * N;
    const int pix = blockIdx.x * 256 + tid;
    const int a0  = blockIdx.y * chunk;
    const int a1  = min(A, a0 + chunk);

    const int x = pix % N;
    const int y = pix / N;
    const float half = (float)(N - 1) * 0.5f;
    const float cx = (float)x - half;
    const float cy = half - (float)y;
    const float q0 = trig[A].x;        // uniform -> s_load

    float acc0 = 0.f, acc1 = 0.f, acc2 = 0.f, acc3 = 0.f;

#pragma unroll 4
    for (int a = a0; a < a1; ++a) {
        float2 t  = trig[a];           // uniform -> s_load_dwordx2
        float f   = fmaf(cx, t.x, fmaf(cy, t.y, q0));
        float i0f = floorf(f);
        float w   = f - i0f;
        int   i0  = (int)i0f;
        int   j   = min(max(i0, -1), P - 1) + 1;   // borders -> zero entries

        half2v w2 = __builtin_amdgcn_cvt_pkrtz(1.0f - w, w);   // (om, wm)
        uint4 e = packed[(size_t)a * PES + j];      // global_load_dwordx4
        acc0 = __builtin_amdgcn_fdot2(as_h2(e.x), w2, acc0, false);
        acc1 = __builtin_amdgcn_fdot2(as_h2(e.y), w2, acc1, false);
        acc2 = __builtin_amdgcn_fdot2(as_h2(e.z), w2, acc2, false);
        acc3 = __builtin_amdgcn_fdot2(as_h2(e.w), w2, acc3, false);
    }

    if (pix < nn) {
        float* op = out + pix;
        atomicAdd(op,                  acc0);
        atomicAdd(op + (size_t)nn,     acc1);
        atomicAdd(op + (size_t)2 * nn, acc2);
        atomicAdd(op + (size_t)3 * nn, acc3);
    }
}

// Generic fallback: direct per-batch kernel (any shape).
__global__ __launch_bounds__(256) void radon_direct_kernel(
    const float* __restrict__ sino,
    const float* __restrict__ thetas,
    const float* __restrict__ positions,
    float* __restrict__ out,
    int A, int P, int N, int BC)
{
    const int nn  = N * N;
    const int pix = blockIdx.x * blockDim.x + threadIdx.x;
    if (pix >= nn) return;
    const float p0     = positions[0];
    const float inv_dp = 1.0f / (positions[1] - p0);
    const int x = pix % N;
    const int y = pix / N;
    const float half = (float)(N - 1) * 0.5f;
    const float cx = (float)x - half;
    const float cy = half - (float)y;
    for (int b = 0; b < BC; ++b) {
        float acc = 0.0f;
        for (int a = 0; a < A; ++a) {
            float th = thetas[a];
            float f  = (cx * cosf(th) + cy * sinf(th) - p0) * inv_dp;
            float i0f = floorf(f);
            int i0 = (int)i0f;
            float w = f - i0f;
            float m = (i0 >= 0 && i0 <= P - 2) ? 1.0f : 0.0f;
            int ic = min(max(i0, 0), P - 2);
            const float* row = sino + ((size_t)b * A + a) * P + ic;
            acc = fmaf(m, fmaf(w, row[1] - row[0], row[0]), acc);
        }
        out[(size_t)b * nn + pix] = acc;
    }
}

extern "C" void kernel_launch(void* const* d_in, const int* in_sizes, int n_in,
                              void* d_out, int out_size, void* d_ws, size_t ws_size,
                              hipStream_t stream) {
    const float* sino      = (const float*)d_in[0];
    const float* thetas    = (const float*)d_in[1];
    const float* positions = (const float*)d_in[2];
    float* out             = (float*)d_out;

    const int A  = in_sizes[1];               // 180
    const int P  = in_sizes[2];               // 384
    const int BC = in_sizes[0] / (A * P);     // B*C = 4
    const int N  = (int)lroundf(sqrtf((float)(out_size / BC)));
    const int nn = N * N;
    const int bstride = A * P;

    const int PES   = (P + 2 + 63) & ~63;     // padded entries per angle
    const int chunk = (A + ACHUNKS - 1) / ACHUNKS;
    const int nout4 = nn;                     // 4*nn floats = nn float4s

    const size_t packed_bytes = (size_t)A * PES * sizeof(uint4);
    const size_t trig_bytes   = (size_t)(A + 1) * sizeof(float2);
    const size_t need = packed_bytes + trig_bytes;

    const bool fast = (BC == 4) && (A <= 1024) && (P >= 2)
                   && ((nn & 255) == 0) && (ws_size >= need);

    if (fast) {
        uint4*  packed = (uint4*)d_ws;
        float2* trig   = (float2*)((char*)d_ws + packed_bytes);

        dim3 block(256);
        const unsigned gp = (unsigned)(((size_t)A * PES > (size_t)nout4
                                        ? (size_t)A * PES : (size_t)nout4) + 255) / 256;
        radon_pack_zero<<<dim3(gp), block, 0, stream>>>(
            sino, thetas, positions, packed, trig, (float4*)out,
            A, P, PES, bstride, nout4);

        dim3 gpart(nn / 256, ACHUNKS);
        radon_gather_at<<<gpart, block, 0, stream>>>(
            packed, trig, out, A, P, PES, N, chunk);
    } else {
        dim3 block(256);
        dim3 grid((nn + 255) / 256);
        radon_direct_kernel<<<grid, block, 0, stream>>>(
            sino, thetas, positions, out, A, P, N, BC);
    }
}

// Round 13
// 72.594 us; speedup vs baseline: 3.4314x; 1.0008x over previous
//
#include <hip/hip_runtime.h>
#include <hip/hip_fp16.h>
#include <cmath>

// Radon backprojection, TWO dispatches:
//   1) pack: zero-padded fp16 (v[j-1],v[j]) pair table [A][PES] (4 batches
//      per 16B entry) + trig table + zero-init of out.
//   2) chunked gather (ACHUNKS=8 -> 32 waves/CU, fdot2 loop, no barriers),
//      WAVE-TILED 16x4: each wave covers a 16x4 pixel sub-tile so its 64
//      lanes span ~13 packed entries (~5 cache lines) per gather instead of
//      ~41 entries (~16 lines) for the 64x1 row layout. Commit via plain
//      atomicAdd (no fences -- R11 showed per-block __threadfence = L2
//      flush storm on 8 XCDs; plain atomics are safe, R12 proved).

#define ACHUNKS 8

typedef __fp16 half2v __attribute__((ext_vector_type(2)));

__device__ __forceinline__ half2v as_h2(unsigned u) {
    union { unsigned u; half2v h; } x; x.u = u; return x.h;
}

__global__ __launch_bounds__(256) void radon_pack_zero(
    const float* __restrict__ sino,
    const float* __restrict__ thetas,
    const float* __restrict__ positions,
    uint4* __restrict__ packed,        // [A][PES]; entry j: (v[j-1], v[j]) x4
    float2* __restrict__ trig,         // [A+1]; trig[A].x = q0
    float4* __restrict__ out4,         // [nn] float4s (= [4][nn] floats) -> zero
    int A, int P, int PES, int bstride, int nout4)
{
    const int gidx = blockIdx.x * 256 + threadIdx.x;
    if (gidx < nout4) out4[gidx] = make_float4(0.f, 0.f, 0.f, 0.f);

    const int a = gidx / PES;
    const int j = gidx - a * PES;
    if (a >= A) return;

    const float p0     = positions[0];
    const float inv_dp = 1.0f / (positions[1] - p0);
    if (j == 0) {
        float th = thetas[a];
        trig[a] = make_float2(cosf(th) * inv_dp, sinf(th) * inv_dp);
        if (a == 0) trig[A] = make_float2(-p0 * inv_dp, 0.0f);
    }

    uint4 e = make_uint4(0, 0, 0, 0);
    if (j >= 1 && j <= P - 1) {
        const float* s = sino + (size_t)a * P + (j - 1);
        unsigned* ep = (unsigned*)&e;
#pragma unroll
        for (int b = 0; b < 4; ++b) {
            float2 v = *(const float2*)(s + (size_t)b * bstride); // dwordx2
            half2v h = __builtin_amdgcn_cvt_pkrtz(v.x, v.y);      // lo=v0 hi=v1
            union { half2v h; unsigned u; } cvt; cvt.h = h;
            ep[b] = cvt.u;
        }
    }
    packed[(size_t)a * PES + j] = e;
}

__global__ __launch_bounds__(256) void radon_gather_at(
    const uint4* __restrict__ packed,  // [A][PES]
    const float2* __restrict__ trig,   // [A+1]
    float* __restrict__ out,           // [4][nn], pre-zeroed
    int A, int P, int PES, int N, int chunk)
{
    const int tid = threadIdx.x;
    const int nn  = N * N;

    // 16x4 wave tiling: block covers a 64x4 pixel tile (4 waves side by side).
    const int w  = tid >> 6;           // wave in block, 0..3
    const int l  = tid & 63;
    const int lx = l & 15;             // 0..15
    const int ly = l >> 4;             // 0..3
    const int tilesx = N >> 6;
    const int bx = blockIdx.x % tilesx;
    const int by = blockIdx.x / tilesx;
    const int x  = (bx << 6) + (w << 4) + lx;
    const int y  = (by << 2) + ly;
    const int pix = y * N + x;

    const int a0  = blockIdx.y * chunk;
    const int a1  = min(A, a0 + chunk);

    const float half = (float)(N - 1) * 0.5f;
    const float cx = (float)x - half;
    const float cy = half - (float)y;
    const float q0 = trig[A].x;        // uniform -> s_load

    float acc0 = 0.f, acc1 = 0.f, acc2 = 0.f, acc3 = 0.f;

#pragma unroll 4
    for (int a = a0; a < a1; ++a) {
        float2 t  = trig[a];           // uniform -> s_load_dwordx2
        float f   = fmaf(cx, t.x, fmaf(cy, t.y, q0));
        float i0f = floorf(f);
        float w_  = f - i0f;
        int   i0  = (int)i0f;
        int   j   = min(max(i0, -1), P - 1) + 1;   // borders -> zero entries

        half2v w2 = __builtin_amdgcn_cvt_pkrtz(1.0f - w_, w_);   // (om, wm)
        uint4 e = packed[(size_t)a * PES + j];      // global_load_dwordx4
        acc0 = __builtin_amdgcn_fdot2(as_h2(e.x), w2, acc0, false);
        acc1 = __builtin_amdgcn_fdot2(as_h2(e.y), w2, acc1, false);
        acc2 = __builtin_amdgcn_fdot2(as_h2(e.z), w2, acc2, false);
        acc3 = __builtin_amdgcn_fdot2(as_h2(e.w), w2, acc3, false);
    }

    float* op = out + pix;
    atomicAdd(op,                  acc0);
    atomicAdd(op + (size_t)nn,     acc1);
    atomicAdd(op + (size_t)2 * nn, acc2);
    atomicAdd(op + (size_t)3 * nn, acc3);
}

// Generic fallback: direct per-batch kernel (any shape).
__global__ __launch_bounds__(256) void radon_direct_kernel(
    const float* __restrict__ sino,
    const float* __restrict__ thetas,
    const float* __restrict__ positions,
    float* __restrict__ out,
    int A, int P, int N, int BC)
{
    const int nn  = N * N;
    const int pix = blockIdx.x * blockDim.x + threadIdx.x;
    if (pix >= nn) return;
    const float p0     = positions[0];
    const float inv_dp = 1.0f / (positions[1] - p0);
    const int x = pix % N;
    const int y = pix / N;
    const float half = (float)(N - 1) * 0.5f;
    const float cx = (float)x - half;
    const float cy = half - (float)y;
    for (int b = 0; b < BC; ++b) {
        float acc = 0.0f;
        for (int a = 0; a < A; ++a) {
            float th = thetas[a];
            float f  = (cx * cosf(th) + cy * sinf(th) - p0) * inv_dp;
            float i0f = floorf(f);
            int i0 = (int)i0f;
            float w = f - i0f;
            float m = (i0 >= 0 && i0 <= P - 2) ? 1.0f : 0.0f;
            int ic = min(max(i0, 0), P - 2);
            const float* row = sino + ((size_t)b * A + a) * P + ic;
            acc = fmaf(m, fmaf(w, row[1] - row[0], row[0]), acc);
        }
        out[(size_t)b * nn + pix] = acc;
    }
}

extern "C" void kernel_launch(void* const* d_in, const int* in_sizes, int n_in,
                              void* d_out, int out_size, void* d_ws, size_t ws_size,
                              hipStream_t stream) {
    const float* sino      = (const float*)d_in[0];
    const float* thetas    = (const float*)d_in[1];
    const float* positions = (const float*)d_in[2];
    float* out             = (float*)d_out;

    const int A  = in_sizes[1];               // 180
    const int P  = in_sizes[2];               // 384
    const int BC = in_sizes[0] / (A * P);     // B*C = 4
    const int N  = (int)lroundf(sqrtf((float)(out_size / BC)));
    const int nn = N * N;
    const int bstride = A * P;

    const int PES   = (P + 2 + 63) & ~63;     // padded entries per angle
    const int chunk = (A + ACHUNKS - 1) / ACHUNKS;
    const int nout4 = nn;                     // 4*nn floats = nn float4s

    const size_t packed_bytes = (size_t)A * PES * sizeof(uint4);
    const size_t trig_bytes   = (size_t)(A + 1) * sizeof(float2);
    const size_t need = packed_bytes + trig_bytes;

    const bool fast = (BC == 4) && (A <= 1024) && (P >= 2)
                   && (N % 64 == 0) && (ws_size >= need);

    if (fast) {
        uint4*  packed = (uint4*)d_ws;
        float2* trig   = (float2*)((char*)d_ws + packed_bytes);

        dim3 block(256);
        const unsigned gp = (unsigned)(((size_t)A * PES > (size_t)nout4
                                        ? (size_t)A * PES : (size_t)nout4) + 255) / 256;
        radon_pack_zero<<<dim3(gp), block, 0, stream>>>(
            sino, thetas, positions, packed, trig, (float4*)out,
            A, P, PES, bstride, nout4);

        dim3 gpart((N / 64) * (N / 4), ACHUNKS);
        radon_gather_at<<<gpart, block, 0, stream>>>(
            packed, trig, out, A, P, PES, N, chunk);
    } else {
        dim3 block(256);
        dim3 grid((nn + 255) / 256);
        radon_direct_kernel<<<grid, block, 0, stream>>>(
            sino, thetas, positions, out, A, P, N, BC);
    }
}

// Round 14
// 71.053 us; speedup vs baseline: 3.5058x; 1.0217x over previous
//
#include <hip/hip_runtime.h>
#include <hip/hip_fp16.h>
#include <cmath>

// Radon backprojection, TWO dispatches:
//   1) pack: zero-padded fp16 (v[j-1],v[j]) pair table [A][PES] (4 batches
//      per 16B entry) + trig table + zero-init of out.
//   2) chunked gather (ACHUNKS=4 -> 16 waves/CU, fdot2 loop, no barriers),
//      16x4 wave tile, committing via plain atomicAdd (no fences).
//
// R13 post-mortem: wave tiling neutral (not line-bound). Residual model:
// atomic epilogue = nn*4*ACHUNKS lane-atomics (~6-9us at ACHUNKS=8, 8
// serialized adds per output dword). R14: ACHUNKS=4 halves atomic count and
// contention; 4 blocks/CU = 16 waves/CU still covers the issue-bound loop.
// R11 lesson stands: NEVER per-block __threadfence on MI355X (L2 flush
// storm across 8 XCDs); plain device-scope atomics are safe (R12).

#define ACHUNKS 4

typedef __fp16 half2v __attribute__((ext_vector_type(2)));

__device__ __forceinline__ half2v as_h2(unsigned u) {
    union { unsigned u; half2v h; } x; x.u = u; return x.h;
}

__global__ __launch_bounds__(256) void radon_pack_zero(
    const float* __restrict__ sino,
    const float* __restrict__ thetas,
    const float* __restrict__ positions,
    uint4* __restrict__ packed,        // [A][PES]; entry j: (v[j-1], v[j]) x4
    float2* __restrict__ trig,         // [A+1]; trig[A].x = q0
    float4* __restrict__ out4,         // [nn] float4s (= [4][nn] floats) -> zero
    int A, int P, int PES, int bstride, int nout4)
{
    const int gidx = blockIdx.x * 256 + threadIdx.x;
    if (gidx < nout4) out4[gidx] = make_float4(0.f, 0.f, 0.f, 0.f);

    const int a = gidx / PES;
    const int j = gidx - a * PES;
    if (a >= A) return;

    const float p0     = positions[0];
    const float inv_dp = 1.0f / (positions[1] - p0);
    if (j == 0) {
        float th = thetas[a];
        trig[a] = make_float2(cosf(th) * inv_dp, sinf(th) * inv_dp);
        if (a == 0) trig[A] = make_float2(-p0 * inv_dp, 0.0f);
    }

    uint4 e = make_uint4(0, 0, 0, 0);
    if (j >= 1 && j <= P - 1) {
        const float* s = sino + (size_t)a * P + (j - 1);
        unsigned* ep = (unsigned*)&e;
#pragma unroll
        for (int b = 0; b < 4; ++b) {
            float2 v = *(const float2*)(s + (size_t)b * bstride); // dwordx2
            half2v h = __builtin_amdgcn_cvt_pkrtz(v.x, v.y);      // lo=v0 hi=v1
            union { half2v h; unsigned u; } cvt; cvt.h = h;
            ep[b] = cvt.u;
        }
    }
    packed[(size_t)a * PES + j] = e;
}

__global__ __launch_bounds__(256) void radon_gather_at(
    const uint4* __restrict__ packed,  // [A][PES]
    const float2* __restrict__ trig,   // [A+1]
    float* __restrict__ out,           // [4][nn], pre-zeroed
    int A, int P, int PES, int N, int chunk)
{
    const int tid = threadIdx.x;
    const int nn  = N * N;

    // 16x4 wave tiling: block covers a 64x4 pixel tile (4 waves side by side).
    const int w  = tid >> 6;           // wave in block, 0..3
    const int l  = tid & 63;
    const int lx = l & 15;             // 0..15
    const int ly = l >> 4;             // 0..3
    const int tilesx = N >> 6;
    const int bx = blockIdx.x % tilesx;
    const int by = blockIdx.x / tilesx;
    const int x  = (bx << 6) + (w << 4) + lx;
    const int y  = (by << 2) + ly;
    const int pix = y * N + x;

    const int a0  = blockIdx.y * chunk;
    const int a1  = min(A, a0 + chunk);

    const float half = (float)(N - 1) * 0.5f;
    const float cx = (float)x - half;
    const float cy = half - (float)y;
    const float q0 = trig[A].x;        // uniform -> s_load

    float acc0 = 0.f, acc1 = 0.f, acc2 = 0.f, acc3 = 0.f;

#pragma unroll 4
    for (int a = a0; a < a1; ++a) {
        float2 t  = trig[a];           // uniform -> s_load_dwordx2
        float f   = fmaf(cx, t.x, fmaf(cy, t.y, q0));
        float i0f = floorf(f);
        float w_  = f - i0f;
        int   i0  = (int)i0f;
        int   j   = min(max(i0, -1), P - 1) + 1;   // borders -> zero entries

        half2v w2 = __builtin_amdgcn_cvt_pkrtz(1.0f - w_, w_);   // (om, wm)
        uint4 e = packed[(size_t)a * PES + j];      // global_load_dwordx4
        acc0 = __builtin_amdgcn_fdot2(as_h2(e.x), w2, acc0, false);
        acc1 = __builtin_amdgcn_fdot2(as_h2(e.y), w2, acc1, false);
        acc2 = __builtin_amdgcn_fdot2(as_h2(e.z), w2, acc2, false);
        acc3 = __builtin_amdgcn_fdot2(as_h2(e.w), w2, acc3, false);
    }

    float* op = out + pix;
    atomicAdd(op,                  acc0);
    atomicAdd(op + (size_t)nn,     acc1);
    atomicAdd(op + (size_t)2 * nn, acc2);
    atomicAdd(op + (size_t)3 * nn, acc3);
}

// Generic fallback: direct per-batch kernel (any shape).
__global__ __launch_bounds__(256) void radon_direct_kernel(
    const float* __restrict__ sino,
    const float* __restrict__ thetas,
    const float* __restrict__ positions,
    float* __restrict__ out,
    int A, int P, int N, int BC)
{
    const int nn  = N * N;
    const int pix = blockIdx.x * blockDim.x + threadIdx.x;
    if (pix >= nn) return;
    const float p0     = positions[0];
    const float inv_dp = 1.0f / (positions[1] - p0);
    const int x = pix % N;
    const int y = pix / N;
    const float half = (float)(N - 1) * 0.5f;
    const float cx = (float)x - half;
    const float cy = half - (float)y;
    for (int b = 0; b < BC; ++b) {
        float acc = 0.0f;
        for (int a = 0; a < A; ++a) {
            float th = thetas[a];
            float f  = (cx * cosf(th) + cy * sinf(th) - p0) * inv_dp;
            float i0f = floorf(f);
            int i0 = (int)i0f;
            float w = f - i0f;
            float m = (i0 >= 0 && i0 <= P - 2) ? 1.0f : 0.0f;
            int ic = min(max(i0, 0), P - 2);
            const float* row = sino + ((size_t)b * A + a) * P + ic;
            acc = fmaf(m, fmaf(w, row[1] - row[0], row[0]), acc);
        }
        out[(size_t)b * nn + pix] = acc;
    }
}

extern "C" void kernel_launch(void* const* d_in, const int* in_sizes, int n_in,
                              void* d_out, int out_size, void* d_ws, size_t ws_size,
                              hipStream_t stream) {
    const float* sino      = (const float*)d_in[0];
    const float* thetas    = (const float*)d_in[1];
    const float* positions = (const float*)d_in[2];
    float* out             = (float*)d_out;

    const int A  = in_sizes[1];               // 180
    const int P  = in_sizes[2];               // 384
    const int BC = in_sizes[0] / (A * P);     // B*C = 4
    const int N  = (int)lroundf(sqrtf((float)(out_size / BC)));
    const int nn = N * N;
    const int bstride = A * P;

    const int PES   = (P + 2 + 63) & ~63;     // padded entries per angle
    const int chunk = (A + ACHUNKS - 1) / ACHUNKS;
    const int nout4 = nn;                     // 4*nn floats = nn float4s

    const size_t packed_bytes = (size_t)A * PES * sizeof(uint4);
    const size_t trig_bytes   = (size_t)(A + 1) * sizeof(float2);
    const size_t need = packed_bytes + trig_bytes;

    const bool fast = (BC == 4) && (A <= 1024) && (P >= 2)
                   && (N % 64 == 0) && (ws_size >= need);

    if (fast) {
        uint4*  packed = (uint4*)d_ws;
        float2* trig   = (float2*)((char*)d_ws + packed_bytes);

        dim3 block(256);
        const unsigned gp = (unsigned)(((size_t)A * PES > (size_t)nout4
                                        ? (size_t)A * PES : (size_t)nout4) + 255) / 256;
        radon_pack_zero<<<dim3(gp), block, 0, stream>>>(
            sino, thetas, positions, packed, trig, (float4*)out,
            A, P, PES, bstride, nout4);

        dim3 gpart((N / 64) * (N / 4), ACHUNKS);
        radon_gather_at<<<gpart, block, 0, stream>>>(
            packed, trig, out, A, P, PES, N, chunk);
    } else {
        dim3 block(256);
        dim3 grid((nn + 255) / 256);
        radon_direct_kernel<<<grid, block, 0, stream>>>(
            sino, thetas, positions, out, A, P, N, BC);
    }
}

// Round 15
// 70.885 us; speedup vs baseline: 3.5141x; 1.0024x over previous
//
#include <hip/hip_runtime.h>
#include <hip/hip_fp16.h>
#include <cmath>

// Radon backprojection, TWO dispatches, atomic-free:
//   1) pack: zero-padded fp16 (v[j-1],v[j]) pair table [A][PES] (4 batches
//      per 16B entry) + trig table.
//   2) gather: one 1024-thread block (16 waves) per 64x4 pixel tile; the 4
//      wave-groups split the angle range 4 ways; partials reduced in LDS
//      (one barrier, block-local only) and committed with plain stores.
//
// R14 post-mortem: atomics are a linear ~0.75us/0.5M term. R15 removes the
// 1M atomics + out zero-init while keeping 16 waves/CU. R11 lesson stands:
// never per-block __threadfence on MI355X; here sync is block-local only.

#define AGROUPS 4

typedef __fp16 half2v __attribute__((ext_vector_type(2)));

__device__ __forceinline__ half2v as_h2(unsigned u) {
    union { unsigned u; half2v h; } x; x.u = u; return x.h;
}

__global__ __launch_bounds__(256) void radon_pack(
    const float* __restrict__ sino,
    const float* __restrict__ thetas,
    const float* __restrict__ positions,
    uint4* __restrict__ packed,        // [A][PES]; entry j: (v[j-1], v[j]) x4
    float2* __restrict__ trig,         // [A+1]; trig[A].x = q0
    int A, int P, int PES, int bstride)
{
    const int gidx = blockIdx.x * 256 + threadIdx.x;
    const int a = gidx / PES;
    const int j = gidx - a * PES;
    if (a >= A) return;

    const float p0     = positions[0];
    const float inv_dp = 1.0f / (positions[1] - p0);
    if (j == 0) {
        float th = thetas[a];
        trig[a] = make_float2(cosf(th) * inv_dp, sinf(th) * inv_dp);
        if (a == 0) trig[A] = make_float2(-p0 * inv_dp, 0.0f);
    }

    uint4 e = make_uint4(0, 0, 0, 0);
    if (j >= 1 && j <= P - 1) {
        const float* s = sino + (size_t)a * P + (j - 1);
        unsigned* ep = (unsigned*)&e;
#pragma unroll
        for (int b = 0; b < 4; ++b) {
            float2 v = *(const float2*)(s + (size_t)b * bstride); // dwordx2
            half2v h = __builtin_amdgcn_cvt_pkrtz(v.x, v.y);      // lo=v0 hi=v1
            union { half2v h; unsigned u; } cvt; cvt.h = h;
            ep[b] = cvt.u;
        }
    }
    packed[(size_t)a * PES + j] = e;
}

__global__ __launch_bounds__(1024) void radon_gather_red(
    const uint4* __restrict__ packed,  // [A][PES]
    const float2* __restrict__ trig,   // [A+1]
    float* __restrict__ out,           // [4][nn]
    int A, int P, int PES, int N, int chunk)
{
    __shared__ float red[AGROUPS][256][4];   // 16 KB

    const int tid = threadIdx.x;
    const int nn  = N * N;
    const int g   = tid >> 8;          // angle group 0..3
    const int p   = tid & 255;         // tile-local pixel 0..255

    // 16x4 wave tiling of the 64x4 tile.
    const int w  = p >> 6;             // wave-tile 0..3
    const int l  = p & 63;
    const int lx = l & 15;
    const int ly = l >> 4;
    const int tilesx = N >> 6;
    const int bx = blockIdx.x % tilesx;
    const int by = blockIdx.x / tilesx;
    const int x  = (bx << 6) + (w << 4) + lx;
    const int y  = (by << 2) + ly;

    const int a0 = g * chunk;
    const int a1 = min(A, a0 + chunk);

    const float half = (float)(N - 1) * 0.5f;
    const float cx = (float)x - half;
    const float cy = half - (float)y;
    const float q0 = trig[A].x;        // uniform -> s_load

    float acc0 = 0.f, acc1 = 0.f, acc2 = 0.f, acc3 = 0.f;

#pragma unroll 4
    for (int a = a0; a < a1; ++a) {
        float2 t  = trig[a];           // uniform -> s_load_dwordx2
        float f   = fmaf(cx, t.x, fmaf(cy, t.y, q0));
        float i0f = floorf(f);
        float w_  = f - i0f;
        int   i0  = (int)i0f;
        int   j   = min(max(i0, -1), P - 1) + 1;   // borders -> zero entries

        half2v w2 = __builtin_amdgcn_cvt_pkrtz(1.0f - w_, w_);   // (om, wm)
        uint4 e = packed[(size_t)a * PES + j];      // global_load_dwordx4
        acc0 = __builtin_amdgcn_fdot2(as_h2(e.x), w2, acc0, false);
        acc1 = __builtin_amdgcn_fdot2(as_h2(e.y), w2, acc1, false);
        acc2 = __builtin_amdgcn_fdot2(as_h2(e.z), w2, acc2, false);
        acc3 = __builtin_amdgcn_fdot2(as_h2(e.w), w2, acc3, false);
    }

    // ds_write_b128: this group's 4-batch partial for pixel p.
    red[g][p][0] = acc0;
    red[g][p][1] = acc1;
    red[g][p][2] = acc2;
    red[g][p][3] = acc3;
    __syncthreads();

    // Reduce phase: thread t -> (batch b2 = t>>8, pixel p2 = t&255).
    const int b2 = tid >> 8;
    const int p2 = tid & 255;
    float s = red[0][p2][b2] + red[1][p2][b2]
            + red[2][p2][b2] + red[3][p2][b2];

    const int w2_ = p2 >> 6;
    const int l2  = p2 & 63;
    const int x2  = (bx << 6) + (w2_ << 4) + (l2 & 15);
    const int y2  = (by << 2) + (l2 >> 4);
    out[(size_t)b2 * nn + y2 * N + x2] = s;
}

// Generic fallback: direct per-batch kernel (any shape).
__global__ __launch_bounds__(256) void radon_direct_kernel(
    const float* __restrict__ sino,
    const float* __restrict__ thetas,
    const float* __restrict__ positions,
    float* __restrict__ out,
    int A, int P, int N, int BC)
{
    const int nn  = N * N;
    const int pix = blockIdx.x * blockDim.x + threadIdx.x;
    if (pix >= nn) return;
    const float p0     = positions[0];
    const float inv_dp = 1.0f / (positions[1] - p0);
    const int x = pix % N;
    const int y = pix / N;
    const float half = (float)(N - 1) * 0.5f;
    const float cx = (float)x - half;
    const float cy = half - (float)y;
    for (int b = 0; b < BC; ++b) {
        float acc = 0.0f;
        for (int a = 0; a < A; ++a) {
            float th = thetas[a];
            float f  = (cx * cosf(th) + cy * sinf(th) - p0) * inv_dp;
            float i0f = floorf(f);
            int i0 = (int)i0f;
            float w = f - i0f;
            float m = (i0 >= 0 && i0 <= P - 2) ? 1.0f : 0.0f;
            int ic = min(max(i0, 0), P - 2);
            const float* row = sino + ((size_t)b * A + a) * P + ic;
            acc = fmaf(m, fmaf(w, row[1] - row[0], row[0]), acc);
        }
        out[(size_t)b * nn + pix] = acc;
    }
}

extern "C" void kernel_launch(void* const* d_in, const int* in_sizes, int n_in,
                              void* d_out, int out_size, void* d_ws, size_t ws_size,
                              hipStream_t stream) {
    const float* sino      = (const float*)d_in[0];
    const float* thetas    = (const float*)d_in[1];
    const float* positions = (const float*)d_in[2];
    float* out             = (float*)d_out;

    const int A  = in_sizes[1];               // 180
    const int P  = in_sizes[2];               // 384
    const int BC = in_sizes[0] / (A * P);     // B*C = 4
    const int N  = (int)lroundf(sqrtf((float)(out_size / BC)));
    const int nn = N * N;
    const int bstride = A * P;

    const int PES   = (P + 2 + 63) & ~63;     // padded entries per angle
    const int chunk = (A + AGROUPS - 1) / AGROUPS;

    const size_t packed_bytes = (size_t)A * PES * sizeof(uint4);
    const size_t trig_bytes   = (size_t)(A + 1) * sizeof(float2);
    const size_t need = packed_bytes + trig_bytes;

    const bool fast = (BC == 4) && (A <= 1024) && (P >= 2)
                   && (N % 64 == 0) && (ws_size >= need);

    if (fast) {
        uint4*  packed = (uint4*)d_ws;
        float2* trig   = (float2*)((char*)d_ws + packed_bytes);

        dim3 block(256);
        dim3 gpack(((unsigned)(A * PES) + 255) / 256);
        radon_pack<<<gpack, block, 0, stream>>>(
            sino, thetas, positions, packed, trig, A, P, PES, bstride);

        dim3 gblock(1024);
        dim3 ggat((N / 64) * (N / 4));
        radon_gather_red<<<ggat, gblock, 0, stream>>>(
            packed, trig, out, A, P, PES, N, chunk);
    } else {
        dim3 block(256);
        dim3 grid((nn + 255) / 256);
        radon_direct_kernel<<<grid, block, 0, stream>>>(
            sino, thetas, positions, out, A, P, N, BC);
    }
}